// Round 9
// baseline (525.677 us; speedup 1.0000x reference)
//
#include <hip/hip_runtime.h>
#include <math.h>

typedef unsigned short u16;
typedef short s16x8 __attribute__((ext_vector_type(8)));
typedef float f32x4 __attribute__((ext_vector_type(4)));
typedef u16 u16x4 __attribute__((ext_vector_type(4)));

#define D 1024
#define MM 2048   // B*S
#define HH 512
#define VV 32000

static __device__ __forceinline__ u16 f2bf(float f) {
    union { float f; unsigned int i; } c; c.f = f;
    unsigned int x = c.i;
    return (u16)((x + 0x7fffu + ((x >> 16) & 1u)) >> 16);  // RNE
}
static __device__ __forceinline__ float sigm(float x) { return 1.0f / (1.0f + expf(-x)); }

// async global->LDS, 16B per lane, LDS dest = wave-uniform base + lane*16
static __device__ __forceinline__ void load_lds16(const u16* g, u16* l) {
    __builtin_amdgcn_global_load_lds(
        (const __attribute__((address_space(1))) unsigned int*)g,
        (__attribute__((address_space(3))) unsigned int*)l, 16, 0, 0);
}

// ---------------- f32 -> bf16 convert (lm_head weights) ----------------
__global__ __launch_bounds__(256) void cvt_kernel(const float* __restrict__ in,
                                                  u16* __restrict__ out, const int n4)
{
    for (int i = blockIdx.x * 256 + threadIdx.x; i < n4; i += gridDim.x * 256) {
        f32x4 v = ((const f32x4*)in)[i];
        u16x4 o;
#pragma unroll
        for (int j = 0; j < 4; j++) o[j] = f2bf(v[j]);
        ((u16x4*)out)[i] = o;
    }
}

// ---------------- concat-convert: Wcat[3072][1024] = {baseW, W1(4 blocks)} ----------------
__global__ __launch_bounds__(256) void cvtcat_kernel(const float* __restrict__ baseW,
    const float* __restrict__ W1, u16* __restrict__ out)
{
    const int N4 = 3072 * 1024 / 4, B4 = 1024 * 1024 / 4;
    for (int i = blockIdx.x * 256 + threadIdx.x; i < N4; i += gridDim.x * 256) {
        f32x4 v = (i < B4) ? ((const f32x4*)baseW)[i] : ((const f32x4*)W1)[i - B4];
        u16x4 o;
#pragma unroll
        for (int j = 0; j < 4; j++) o[j] = f2bf(v[j]);
        ((u16x4*)out)[i] = o;
    }
}

// ---------------- embed ----------------
__global__ __launch_bounds__(256) void embed_kernel(const int* __restrict__ ids,
    const float* __restrict__ emb, const float* __restrict__ pos, float* __restrict__ h)
{
    const int m = blockIdx.x;
    const int s = m & 1023;
    const long id = ids[m];
    const int d = threadIdx.x * 4;
    f32x4 ev = *(const f32x4*)&emb[id * D + d];
    f32x4 pv = *(const f32x4*)&pos[(long)s * D + d];
    f32x4 o;
#pragma unroll
    for (int i = 0; i < 4; i++) o[i] = ev[i] + pv[i];
    *(f32x4*)&h[(long)m * D + d] = o;
}

// ---------------- layernorm(f32) -> bf16 ----------------
__global__ __launch_bounds__(256) void ln_bf16_kernel(const float* __restrict__ h,
    u16* __restrict__ out, const float* __restrict__ g, const float* __restrict__ b)
{
    const int row = blockIdx.x;
    const int d = threadIdx.x * 4;
    f32x4 x = *(const f32x4*)&h[(long)row * D + d];
    float s = x[0] + x[1] + x[2] + x[3];
    float ss = x[0]*x[0] + x[1]*x[1] + x[2]*x[2] + x[3]*x[3];
#pragma unroll
    for (int off = 32; off; off >>= 1) { s += __shfl_xor(s, off); ss += __shfl_xor(ss, off); }
    __shared__ float red[8];
    const int wid = threadIdx.x >> 6;
    if ((threadIdx.x & 63) == 0) { red[wid] = s; red[4 + wid] = ss; }
    __syncthreads();
    s = red[0] + red[1] + red[2] + red[3];
    ss = red[4] + red[5] + red[6] + red[7];
    const float mu = s * (1.0f / D);
    const float rstd = rsqrtf(ss * (1.0f / D) - mu * mu + 1e-5f);
    f32x4 gv = *(const f32x4*)&g[d];
    f32x4 bv = *(const f32x4*)&b[d];
    u16x4 o;
#pragma unroll
    for (int i = 0; i < 4; i++) o[i] = f2bf((x[i] - mu) * rstd * gv[i] + bv[i]);
    *(u16x4*)&out[(long)row * D + d] = o;
}

// ---------------- h = LN(h + 0.3*C) ----------------
__global__ __launch_bounds__(256) void resln_kernel(float* __restrict__ h,
    const float* __restrict__ c, const float* __restrict__ g, const float* __restrict__ b)
{
    const int row = blockIdx.x;
    const int d = threadIdx.x * 4;
    f32x4 x = *(const f32x4*)&h[(long)row * D + d];
    f32x4 cv = *(const f32x4*)&c[(long)row * D + d];
#pragma unroll
    for (int i = 0; i < 4; i++) x[i] += 0.3f * cv[i];
    float s = x[0] + x[1] + x[2] + x[3];
    float ss = x[0]*x[0] + x[1]*x[1] + x[2]*x[2] + x[3]*x[3];
#pragma unroll
    for (int off = 32; off; off >>= 1) { s += __shfl_xor(s, off); ss += __shfl_xor(ss, off); }
    __shared__ float red[8];
    const int wid = threadIdx.x >> 6;
    if ((threadIdx.x & 63) == 0) { red[wid] = s; red[4 + wid] = ss; }
    __syncthreads();
    s = red[0] + red[1] + red[2] + red[3];
    ss = red[4] + red[5] + red[6] + red[7];
    const float mu = s * (1.0f / D);
    const float rstd = rsqrtf(ss * (1.0f / D) - mu * mu + 1e-5f);
    f32x4 gv = *(const f32x4*)&g[d];
    f32x4 bv = *(const f32x4*)&b[d];
    f32x4 o;
#pragma unroll
    for (int i = 0; i < 4; i++) o[i] = (x[i] - mu) * rstd * gv[i] + bv[i];
    *(f32x4*)&h[(long)row * D + d] = o;
}

// ---------------- exc scales ----------------
__global__ void exc_kernel(const float* __restrict__ pW, const float* __restrict__ pb,
                           float* __restrict__ sc)
{
    if (threadIdx.x == 0 && blockIdx.x == 0) {
        const float NS = 1.0f / (1.0f + expf(-0.70710678118654752f));
        float e[4], sum = 0.0f;
        for (int k = 0; k < 4; k++) {
            float a = pb[k];
            for (int j = 0; j < 4; j++) a += 0.5f * pW[k * 4 + j];
            e[k] = 0.6f * sigm(a) + 0.4f * NS;
            sum += e[k];
        }
        for (int k = 0; k < 4; k++) sc[k] = e[k] / sum;
    }
}

// ---------------- W2eff scale+convert ----------------
__global__ __launch_bounds__(256) void scale_w2_kernel(
    const float* __restrict__ W2l, const float* __restrict__ gatel,
    const float* __restrict__ tors, const float* __restrict__ sc,
    u16* __restrict__ W2eff)
{
    const int n = blockIdx.x >> 1;
    const int half = blockIdx.x & 1;
    const int kh = half * 1024 + threadIdx.x * 4;
    const int k = kh >> 9;
    const int hh = kh & 511;
    const float f = sigm(gatel[k * D + n] + tors[n]) * sc[k];
    f32x4 w = *(const f32x4*)&W2l[((long)k * D + n) * HH + hh];
    u16x4 o;
#pragma unroll
    for (int i = 0; i < 4; i++) o[i] = f2bf(w[i] * f);
    *(u16x4*)&W2eff[(long)n * 2048 + kh] = o;
}

// ================= unified GEMM: 128x128 tile, 4 waves, BK=32, fragment-linear LDS =================
// C[M,N] = A[M,K] @ W[N,K]^T, bf16 in, f32 accum. m97 2-barrier loop; ~3 blocks/CU resident
// (16 KB LDS + ~130 regs) so one block's epilogue/barrier overlaps another's K-loop (m114).
// LDS layout: 16 chunks of 1KB; chunk = one 16x32 MFMA fragment in lane order -> all
// ds_read/ds_write are base+lane*16: ZERO bank conflicts. Staging pre-swizzles global addr.
// EPI 0: f32 store, 256B-coalesced via per-wave LDS transpose slice (lm_head).
// EPI 3: mixed -> n<1024: f32 C (ld 1024); n>=1024: gelu->bf16 t (ld 2048). (fused base+W1)
// EPI 4: f32 atomicAdd (split-K W2; blockIdx.z = K-quarter).
template<int EPI>
__global__ __launch_bounds__(256) void gemm_t(
    const u16* __restrict__ A, const u16* __restrict__ W,
    float* __restrict__ Cf, u16* __restrict__ Cb,
    const int Kloop, const int ldk, const long ldc)
{
    if (EPI == 4) { A += blockIdx.z * 512; W += blockIdx.z * 512; }

    // bijective XCD-chunk swizzle (all grids have nwg % 8 == 0)
    const int gx = gridDim.x;
    const int nwg = gx * gridDim.y;
    int lin = blockIdx.y * gx + blockIdx.x;
    lin = (lin & 7) * (nwg >> 3) + (lin >> 3);
    const int bm = (lin % gx) * 128;
    const int bn = (lin / gx) * 128;

    __shared__ __align__(16) u16 AB[8192];                 // 16 chunks x 512 u16 = 16 KB
    __shared__ float epi[(EPI == 0 ? 4 : 1)][16][72];      // lm_head transpose slices

    const int tid = threadIdx.x, lane = tid & 63, w = tid >> 6;
    const int wm = w >> 1, wn = w & 1;          // wave -> 64x64 quadrant
    const int l15 = lane & 15, lk8 = (lane >> 4) * 8;

    // staging: wave w owns chunks {w, w+4, w+8, w+12}; c<8 = A frag-row c, else B frag-row c-8
    const u16* src[4];
    u16* dst[4];
#pragma unroll
    for (int ci = 0; ci < 4; ++ci) {
        const int c = w + ci * 4;
        src[ci] = (c < 8 ? A + (long)(bm + c * 16 + l15) * ldk
                         : W + (long)(bn + (c - 8) * 16 + l15) * ldk) + lk8;
        dst[ci] = AB + c * 512;
    }

    f32x4 acc[4][4];
#pragma unroll
    for (int i = 0; i < 4; ++i)
#pragma unroll
        for (int j = 0; j < 4; ++j) acc[i][j] = f32x4{0.f, 0.f, 0.f, 0.f};

    for (int k0 = 0; k0 < Kloop; k0 += 32) {
        __syncthreads();                       // prev-iter reads done before overwrite
#pragma unroll
        for (int ci = 0; ci < 4; ++ci) load_lds16(src[ci] + k0, dst[ci]);
        __syncthreads();                       // compiler drains vmcnt(0) -> LDS ready
        s16x8 a[4], b[4];
#pragma unroll
        for (int i = 0; i < 4; ++i) a[i] = *(const s16x8*)(AB + (wm * 4 + i) * 512 + lane * 8);
#pragma unroll
        for (int j = 0; j < 4; ++j) b[j] = *(const s16x8*)(AB + (8 + wn * 4 + j) * 512 + lane * 8);
#pragma unroll
        for (int i = 0; i < 4; ++i)
#pragma unroll
            for (int j = 0; j < 4; ++j)
                acc[i][j] = __builtin_amdgcn_mfma_f32_16x16x32_bf16(a[i], b[j], acc[i][j], 0, 0, 0);
    }

    // C/D layout (verified): col = lane&15, row = (lane>>4)*4 + reg
    const int r0 = (lane >> 4) * 4;
    if (EPI == 0) {
        // coalesced epilogue: per-wave LDS transpose -> f32x4 stores (256B segments)
#pragma unroll
        for (int i = 0; i < 4; ++i) {
#pragma unroll
            for (int j = 0; j < 4; ++j)
#pragma unroll
                for (int rr = 0; rr < 4; ++rr)
                    epi[w][r0 + rr][j * 16 + l15] = acc[i][j][rr];
#pragma unroll
            for (int p = 0; p < 4; ++p) {
                const int r16 = p * 4 + (lane >> 4);
                f32x4 v = *(const f32x4*)&epi[w][r16][l15 * 4];
                *(f32x4*)&Cf[(long)(bm + wm * 64 + i * 16 + r16) * ldc + bn + wn * 64 + l15 * 4] = v;
            }
        }
    } else {
#pragma unroll
        for (int i = 0; i < 4; ++i) {
#pragma unroll
            for (int j = 0; j < 4; ++j) {
                const int n = bn + wn * 64 + j * 16 + l15;
#pragma unroll
                for (int rr = 0; rr < 4; ++rr) {
                    const int m = bm + wm * 64 + i * 16 + r0 + rr;
                    const float v = acc[i][j][rr];
                    if (EPI == 3) {
                        if (n < 1024) {
                            Cf[(long)m * 1024 + n] = v;
                        } else {
                            const float gel = 0.5f * v * (1.0f + erff(v * 0.70710678118654752f));
                            Cb[(long)m * 2048 + (n - 1024)] = f2bf(gel);
                        }
                    } else {  // EPI == 4
                        atomicAdd(&Cf[(long)m * ldc + n], v);
                    }
                }
            }
        }
    }
}

extern "C" void kernel_launch(void* const* d_in, const int* in_sizes, int n_in,
                              void* d_out, int out_size, void* d_ws, size_t ws_size,
                              hipStream_t stream)
{
    (void)in_sizes; (void)n_in; (void)out_size; (void)ws_size;
    const int*   ids   = (const int*)d_in[0];
    const float* emb   = (const float*)d_in[1];
    const float* pos   = (const float*)d_in[2];
    const float* tors  = (const float*)d_in[3];
    const float* ln1g  = (const float*)d_in[4];
    const float* ln1b  = (const float*)d_in[5];
    const float* baseW = (const float*)d_in[6];
    const float* W1    = (const float*)d_in[7];
    const float* W2    = (const float*)d_in[8];
    const float* gate  = (const float*)d_in[9];
    const float* propW = (const float*)d_in[10];
    const float* propb = (const float*)d_in[11];
    const float* ln2g  = (const float*)d_in[12];
    const float* ln2b  = (const float*)d_in[13];
    const float* outg  = (const float*)d_in[14];
    const float* outb  = (const float*)d_in[15];
    const float* lmW   = (const float*)d_in[16];

    char* ws = (char*)d_ws;
    float* h     = (float*)(ws);                    // 0..8 MB    [2048][1024] f32
    u16*   hn    = (u16*)  (ws + (8l  << 20));      // 8..12 MB   [2048][1024] bf16
    // layer-phase buffers (dead after the loop):
    u16*   Wcat  = (u16*)  (ws + (12l << 20));      // 12..18 MB  [3072][1024] bf16
    float* C     = (float*)(ws + (18l << 20));      // 18..26 MB  [2048][1024] f32
    u16*   t     = (u16*)  (ws + (26l << 20));      // 26..34 MB  [2048][2048] bf16
    u16*   W2eff = (u16*)  (ws + (34l << 20));      // 34..38 MB  [1024][2048] bf16
    float* sc    = (float*)(ws + (38l << 20));      // 16 B
    // final-phase buffer, overlaid on dead layer buffers:
    u16*   lmWbf = (u16*)  (ws + (12l << 20));      // 12..74.5 MB [32000][1024] bf16

    embed_kernel<<<MM, 256, 0, stream>>>(ids, emb, pos, h);

    for (int l = 0; l < 2; l++) {
        exc_kernel<<<1, 64, 0, stream>>>(propW + l * 16, propb + l * 4, sc);
        ln_bf16_kernel<<<MM, 256, 0, stream>>>(h, hn, ln1g + (long)l * D, ln1b + (long)l * D);
        cvtcat_kernel<<<1024, 256, 0, stream>>>(
            baseW + (long)l * D * D, W1 + (long)l * 4 * HH * D, Wcat);
        scale_w2_kernel<<<2048, 256, 0, stream>>>(
            W2 + (long)l * 4 * D * HH, gate + (long)l * 4 * D, tors, sc, W2eff);
        // {base -> C(f32), t = gelu(hn @ W1^T)} in ONE GEMM: N = 3072, 384 blocks
        gemm_t<3><<<dim3(16, 24), 256, 0, stream>>>(
            hn, Wcat, C, t, 1024, 1024, 0);
        // C += t @ W2eff^T, split-K x4 (atomicAdd), 512 blocks
        gemm_t<4><<<dim3(16, 8, 4), 256, 0, stream>>>(
            t, W2eff, C, nullptr, 512, 2048, 1024);
        resln_kernel<<<MM, 256, 0, stream>>>(h, C, ln2g + (long)l * D, ln2b + (long)l * D);
    }

    ln_bf16_kernel<<<MM, 256, 0, stream>>>(h, hn, outg, outb);
    cvt_kernel<<<2048, 256, 0, stream>>>(lmW, lmWbf, VV * D / 4);
    // lm_head: coalesced-epilogue GEMM, 4000 blocks
    gemm_t<0><<<dim3(16, 250), 256, 0, stream>>>(
        hn, lmWbf, (float*)d_out, nullptr, 1024, 1024, VV);
}

// Round 10
// 441.866 us; speedup vs baseline: 1.1897x; 1.1897x over previous
//
#include <hip/hip_runtime.h>
#include <math.h>

typedef unsigned short u16;
typedef short s16x8 __attribute__((ext_vector_type(8)));
typedef float f32x4 __attribute__((ext_vector_type(4)));
typedef u16 u16x4 __attribute__((ext_vector_type(4)));

#define D 1024
#define MM 2048   // B*S
#define HH 512
#define VV 32000

static __device__ __forceinline__ u16 f2bf(float f) {
    union { float f; unsigned int i; } c; c.f = f;
    unsigned int x = c.i;
    return (u16)((x + 0x7fffu + ((x >> 16) & 1u)) >> 16);  // RNE
}
static __device__ __forceinline__ float sigm(float x) { return 1.0f / (1.0f + expf(-x)); }

// async global->LDS, 16B per lane, LDS dest = wave-uniform base + lane*16
static __device__ __forceinline__ void load_lds16(const u16* g, u16* l) {
    __builtin_amdgcn_global_load_lds(
        (const __attribute__((address_space(1))) unsigned int*)g,
        (__attribute__((address_space(3))) unsigned int*)l, 16, 0, 0);
}

// ---------------- f32 -> bf16 convert, NT input (read-once stream) ----------------
__global__ __launch_bounds__(256) void cvt_kernel(const float* __restrict__ in,
                                                  u16* __restrict__ out, const int n4)
{
    for (int i = blockIdx.x * 256 + threadIdx.x; i < n4; i += gridDim.x * 256) {
        f32x4 v = __builtin_nontemporal_load((const f32x4*)in + i);
        u16x4 o;
#pragma unroll
        for (int j = 0; j < 4; j++) o[j] = f2bf(v[j]);
        ((u16x4*)out)[i] = o;
    }
}

// ---------------- concat-convert: Wcat[3072][1024] = {baseW, W1(4 blocks)} ----------------
__global__ __launch_bounds__(256) void cvtcat_kernel(const float* __restrict__ baseW,
    const float* __restrict__ W1, u16* __restrict__ out)
{
    const int N4 = 3072 * 1024 / 4, B4 = 1024 * 1024 / 4;
    for (int i = blockIdx.x * 256 + threadIdx.x; i < N4; i += gridDim.x * 256) {
        f32x4 v = (i < B4) ? __builtin_nontemporal_load((const f32x4*)baseW + i)
                           : __builtin_nontemporal_load((const f32x4*)W1 + (i - B4));
        u16x4 o;
#pragma unroll
        for (int j = 0; j < 4; j++) o[j] = f2bf(v[j]);
        ((u16x4*)out)[i] = o;
    }
}

// ---------------- embed ----------------
__global__ __launch_bounds__(256) void embed_kernel(const int* __restrict__ ids,
    const float* __restrict__ emb, const float* __restrict__ pos, float* __restrict__ h)
{
    const int m = blockIdx.x;
    const int s = m & 1023;
    const long id = ids[m];
    const int d = threadIdx.x * 4;
    f32x4 ev = *(const f32x4*)&emb[id * D + d];
    f32x4 pv = *(const f32x4*)&pos[(long)s * D + d];
    f32x4 o;
#pragma unroll
    for (int i = 0; i < 4; i++) o[i] = ev[i] + pv[i];
    *(f32x4*)&h[(long)m * D + d] = o;
}

// ---------------- layernorm(f32) -> bf16 ----------------
__global__ __launch_bounds__(256) void ln_bf16_kernel(const float* __restrict__ h,
    u16* __restrict__ out, const float* __restrict__ g, const float* __restrict__ b)
{
    const int row = blockIdx.x;
    const int d = threadIdx.x * 4;
    f32x4 x = *(const f32x4*)&h[(long)row * D + d];
    float s = x[0] + x[1] + x[2] + x[3];
    float ss = x[0]*x[0] + x[1]*x[1] + x[2]*x[2] + x[3]*x[3];
#pragma unroll
    for (int off = 32; off; off >>= 1) { s += __shfl_xor(s, off); ss += __shfl_xor(ss, off); }
    __shared__ float red[8];
    const int wid = threadIdx.x >> 6;
    if ((threadIdx.x & 63) == 0) { red[wid] = s; red[4 + wid] = ss; }
    __syncthreads();
    s = red[0] + red[1] + red[2] + red[3];
    ss = red[4] + red[5] + red[6] + red[7];
    const float mu = s * (1.0f / D);
    const float rstd = rsqrtf(ss * (1.0f / D) - mu * mu + 1e-5f);
    f32x4 gv = *(const f32x4*)&g[d];
    f32x4 bv = *(const f32x4*)&b[d];
    u16x4 o;
#pragma unroll
    for (int i = 0; i < 4; i++) o[i] = f2bf((x[i] - mu) * rstd * gv[i] + bv[i]);
    *(u16x4*)&out[(long)row * D + d] = o;
}

// ---------------- h = LN(h + 0.3*C) ----------------
__global__ __launch_bounds__(256) void resln_kernel(float* __restrict__ h,
    const float* __restrict__ c, const float* __restrict__ g, const float* __restrict__ b)
{
    const int row = blockIdx.x;
    const int d = threadIdx.x * 4;
    f32x4 x = *(const f32x4*)&h[(long)row * D + d];
    f32x4 cv = *(const f32x4*)&c[(long)row * D + d];
#pragma unroll
    for (int i = 0; i < 4; i++) x[i] += 0.3f * cv[i];
    float s = x[0] + x[1] + x[2] + x[3];
    float ss = x[0]*x[0] + x[1]*x[1] + x[2]*x[2] + x[3]*x[3];
#pragma unroll
    for (int off = 32; off; off >>= 1) { s += __shfl_xor(s, off); ss += __shfl_xor(ss, off); }
    __shared__ float red[8];
    const int wid = threadIdx.x >> 6;
    if ((threadIdx.x & 63) == 0) { red[wid] = s; red[4 + wid] = ss; }
    __syncthreads();
    s = red[0] + red[1] + red[2] + red[3];
    ss = red[4] + red[5] + red[6] + red[7];
    const float mu = s * (1.0f / D);
    const float rstd = rsqrtf(ss * (1.0f / D) - mu * mu + 1e-5f);
    f32x4 gv = *(const f32x4*)&g[d];
    f32x4 bv = *(const f32x4*)&b[d];
    f32x4 o;
#pragma unroll
    for (int i = 0; i < 4; i++) o[i] = (x[i] - mu) * rstd * gv[i] + bv[i];
    *(f32x4*)&h[(long)row * D + d] = o;
}

// ---------------- exc scales ----------------
__global__ void exc_kernel(const float* __restrict__ pW, const float* __restrict__ pb,
                           float* __restrict__ sc)
{
    if (threadIdx.x == 0 && blockIdx.x == 0) {
        const float NS = 1.0f / (1.0f + expf(-0.70710678118654752f));
        float e[4], sum = 0.0f;
        for (int k = 0; k < 4; k++) {
            float a = pb[k];
            for (int j = 0; j < 4; j++) a += 0.5f * pW[k * 4 + j];
            e[k] = 0.6f * sigm(a) + 0.4f * NS;
            sum += e[k];
        }
        for (int k = 0; k < 4; k++) sc[k] = e[k] / sum;
    }
}

// ---------------- W2eff scale+convert ----------------
__global__ __launch_bounds__(256) void scale_w2_kernel(
    const float* __restrict__ W2l, const float* __restrict__ gatel,
    const float* __restrict__ tors, const float* __restrict__ sc,
    u16* __restrict__ W2eff)
{
    const int n = blockIdx.x >> 1;
    const int half = blockIdx.x & 1;
    const int kh = half * 1024 + threadIdx.x * 4;
    const int k = kh >> 9;
    const int hh = kh & 511;
    const float f = sigm(gatel[k * D + n] + tors[n]) * sc[k];
    f32x4 w = __builtin_nontemporal_load((const f32x4*)&W2l[((long)k * D + n) * HH + hh]);
    u16x4 o;
#pragma unroll
    for (int i = 0; i < 4; i++) o[i] = f2bf(w[i] * f);
    *(u16x4*)&W2eff[(long)n * 2048 + kh] = o;
}

// ---------------- layer GEMM: 128x128 tile, 4 waves, BK=32, fragment-linear LDS ----------------
// EPI 3: mixed -> n<1024: f32 C (ld 1024); n>=1024: gelu->bf16 t (ld 2048). (fused base+W1)
// EPI 4: f32 atomicAdd (split-K W2; blockIdx.z = K-quarter).
template<int EPI>
__global__ __launch_bounds__(256) void gemm_t(
    const u16* __restrict__ A, const u16* __restrict__ W,
    float* __restrict__ Cf, u16* __restrict__ Cb,
    const int Kloop, const int ldk, const long ldc)
{
    if (EPI == 4) { A += blockIdx.z * 512; W += blockIdx.z * 512; }

    const int gx = gridDim.x;
    const int nwg = gx * gridDim.y;
    int lin = blockIdx.y * gx + blockIdx.x;
    lin = (lin & 7) * (nwg >> 3) + (lin >> 3);
    const int bm = (lin % gx) * 128;
    const int bn = (lin / gx) * 128;

    __shared__ __align__(16) u16 AB[8192];   // 16 chunks x 512 u16 = 16 KB

    const int tid = threadIdx.x, lane = tid & 63, w = tid >> 6;
    const int wm = w >> 1, wn = w & 1;
    const int l15 = lane & 15, lk8 = (lane >> 4) * 8;

    const u16* src[4];
    u16* dst[4];
#pragma unroll
    for (int ci = 0; ci < 4; ++ci) {
        const int c = w + ci * 4;
        src[ci] = (c < 8 ? A + (long)(bm + c * 16 + l15) * ldk
                         : W + (long)(bn + (c - 8) * 16 + l15) * ldk) + lk8;
        dst[ci] = AB + c * 512;
    }

    f32x4 acc[4][4];
#pragma unroll
    for (int i = 0; i < 4; ++i)
#pragma unroll
        for (int j = 0; j < 4; ++j) acc[i][j] = f32x4{0.f, 0.f, 0.f, 0.f};

    for (int k0 = 0; k0 < Kloop; k0 += 32) {
        __syncthreads();
#pragma unroll
        for (int ci = 0; ci < 4; ++ci) load_lds16(src[ci] + k0, dst[ci]);
        __syncthreads();
        s16x8 a[4], b[4];
#pragma unroll
        for (int i = 0; i < 4; ++i) a[i] = *(const s16x8*)(AB + (wm * 4 + i) * 512 + lane * 8);
#pragma unroll
        for (int j = 0; j < 4; ++j) b[j] = *(const s16x8*)(AB + (8 + wn * 4 + j) * 512 + lane * 8);
#pragma unroll
        for (int i = 0; i < 4; ++i)
#pragma unroll
            for (int j = 0; j < 4; ++j)
                acc[i][j] = __builtin_amdgcn_mfma_f32_16x16x32_bf16(a[i], b[j], acc[i][j], 0, 0, 0);
    }

    const int r0 = (lane >> 4) * 4;
#pragma unroll
    for (int i = 0; i < 4; ++i) {
#pragma unroll
        for (int j = 0; j < 4; ++j) {
            const int n = bn + wn * 64 + j * 16 + l15;
#pragma unroll
            for (int rr = 0; rr < 4; ++rr) {
                const int m = bm + wm * 64 + i * 16 + r0 + rr;
                const float v = acc[i][j][rr];
                if (EPI == 3) {
                    if (n < 1024) {
                        Cf[(long)m * 1024 + n] = v;
                    } else {
                        const float gel = 0.5f * v * (1.0f + erff(v * 0.70710678118654752f));
                        Cb[(long)m * 2048 + (n - 1024)] = f2bf(gel);
                    }
                } else {  // EPI == 4
                    atomicAdd(&Cf[(long)m * ldc + n], v);
                }
            }
        }
    }
}

// ================= lm_head GEMM: 256x256, BK=64, 2 phases/K-tile, frag prefetch, NT stores ========
#define AU16  16384
#define HALFU 8192
#define BB0   32768

__global__ __launch_bounds__(512, 2) void gemm256_kernel(
    const u16* __restrict__ Ag, const u16* __restrict__ Wg, float* __restrict__ C)
{
    __shared__ __align__(16) u16 lds[65536];  // 128KB

    const int nwg = gridDim.x * gridDim.y;
    int lin = blockIdx.y * gridDim.x + blockIdx.x;
    lin = (lin & 7) * (nwg >> 3) + (lin >> 3);
    const int bm = (lin & 7) * 256;
    const int bn = (lin >> 3) * 256;

    const int tid = threadIdx.x;
    const int lane = tid & 63;
    const int w = tid >> 6;
    const int wm = w >> 2;
    const int wn = w & 3;

    const u16* aSrc = Ag + (long)(bm + w * 16 + (lane & 15)) * 1024 + ((lane >> 4) * 8);
    const u16* bSrc = Wg + (long)(bn + w * 16 + (lane & 15)) * 1024 + ((lane >> 4) * 8);
    u16* aDst = lds + w * 1024;
    u16* bDst = lds + BB0 + w * 1024;

    auto stageA = [&](int kt, int b, int kk) {
        const long co = (long)kt * 64 + kk * 32;
        load_lds16(aSrc + co,               aDst + b * AU16 + kk * 512);
        load_lds16(aSrc + co + 128 * 1024L, aDst + b * AU16 + HALFU + kk * 512);
    };
    auto stageB = [&](int kt, int b, int kk) {
        const long co = (long)kt * 64 + kk * 32;
        load_lds16(bSrc + co,               bDst + b * AU16 + kk * 512);
        load_lds16(bSrc + co + 128 * 1024L, bDst + b * AU16 + HALFU + kk * 512);
    };

    const u16* aRd = lds + wm * HALFU + lane * 8;
    const u16* bRd = lds + BB0 + (wn >> 1) * HALFU + (wn & 1) * 4096 + lane * 8;

    f32x4 acc[8][4];
#pragma unroll
    for (int i = 0; i < 8; ++i)
#pragma unroll
        for (int j = 0; j < 4; ++j) acc[i][j] = f32x4{0.f, 0.f, 0.f, 0.f};

    s16x8 F0[12], F1[12];

    stageA(0, 0, 0); stageB(0, 0, 0);
    stageA(0, 0, 1); stageB(0, 0, 1);
    stageA(1, 1, 0); stageB(1, 1, 0);
    asm volatile("s_waitcnt vmcnt(4)" ::: "memory");
    __builtin_amdgcn_s_barrier();
    __builtin_amdgcn_sched_barrier(0);

#pragma unroll
    for (int i = 0; i < 8; ++i) F0[i] = *(const s16x8*)(aRd + i * 1024);
#pragma unroll
    for (int j = 0; j < 4; ++j) F0[8 + j] = *(const s16x8*)(bRd + j * 1024);

    auto phase = [&](int p, s16x8 (&fu)[12], s16x8 (&fl)[12]) {
        const int pr = p + 1;
        const int Tr = (pr >> 1) & 15, kkr = pr & 1, br = Tr & 1;
        const u16* aR = aRd + br * AU16 + kkr * 512;
        const u16* bR = bRd + br * AU16 + kkr * 512;
#pragma unroll
        for (int i = 0; i < 8; ++i) fl[i] = *(const s16x8*)(aR + i * 1024);
#pragma unroll
        for (int j = 0; j < 4; ++j) fl[8 + j] = *(const s16x8*)(bR + j * 1024);
        const int us = 6 + 2 * p;
        const int Ts = (us >> 2) & 15, kks = (us >> 1) & 1, bs = Ts & 1;
        stageA(Ts, bs, kks);
        stageB(Ts, bs, kks);
        __builtin_amdgcn_sched_barrier(0);
        __builtin_amdgcn_s_setprio(1);
#pragma unroll
        for (int j = 0; j < 4; ++j)
#pragma unroll
            for (int i = 0; i < 8; ++i)
                acc[i][j] = __builtin_amdgcn_mfma_f32_16x16x32_bf16(fu[i], fu[8 + j], acc[i][j], 0, 0, 0);
        __builtin_amdgcn_s_setprio(0);
        __builtin_amdgcn_sched_barrier(0);
        asm volatile("s_waitcnt vmcnt(4)" ::: "memory");
        __builtin_amdgcn_s_barrier();
        __builtin_amdgcn_sched_barrier(0);
    };

    for (int p = 0; p < 32; p += 2) {
        phase(p,     F0, F1);
        phase(p + 1, F1, F0);
    }

    asm volatile("s_waitcnt vmcnt(0)" ::: "memory");

    // epilogue: NT stores — d_out is never re-read; keep L2 for W/A streams
    const int r0 = (lane >> 4) * 4;
    const int cl = lane & 15;
#pragma unroll
    for (int i = 0; i < 8; ++i)
#pragma unroll
        for (int j = 0; j < 4; ++j) {
            const long m = bm + wm * 128 + i * 16 + r0;
            const int n = bn + wn * 64 + j * 16 + cl;
#pragma unroll
            for (int rr = 0; rr < 4; ++rr)
                __builtin_nontemporal_store(acc[i][j][rr], &C[(m + rr) * (long)VV + n]);
        }
}

extern "C" void kernel_launch(void* const* d_in, const int* in_sizes, int n_in,
                              void* d_out, int out_size, void* d_ws, size_t ws_size,
                              hipStream_t stream)
{
    (void)in_sizes; (void)n_in; (void)out_size; (void)ws_size;
    const int*   ids   = (const int*)d_in[0];
    const float* emb   = (const float*)d_in[1];
    const float* pos   = (const float*)d_in[2];
    const float* tors  = (const float*)d_in[3];
    const float* ln1g  = (const float*)d_in[4];
    const float* ln1b  = (const float*)d_in[5];
    const float* baseW = (const float*)d_in[6];
    const float* W1    = (const float*)d_in[7];
    const float* W2    = (const float*)d_in[8];
    const float* gate  = (const float*)d_in[9];
    const float* propW = (const float*)d_in[10];
    const float* propb = (const float*)d_in[11];
    const float* ln2g  = (const float*)d_in[12];
    const float* ln2b  = (const float*)d_in[13];
    const float* outg  = (const float*)d_in[14];
    const float* outb  = (const float*)d_in[15];
    const float* lmW   = (const float*)d_in[16];

    char* ws = (char*)d_ws;
    float* h     = (float*)(ws);                    // 0..8 MB
    u16*   hn    = (u16*)  (ws + (8l  << 20));      // 8..12 MB
    u16*   Wcat  = (u16*)  (ws + (12l << 20));      // 12..18 MB
    float* C     = (float*)(ws + (18l << 20));      // 18..26 MB
    u16*   t     = (u16*)  (ws + (26l << 20));      // 26..34 MB
    u16*   W2eff = (u16*)  (ws + (34l << 20));      // 34..38 MB
    float* sc    = (float*)(ws + (38l << 20));      // 16 B
    u16*   lmWbf = (u16*)  (ws + (12l << 20));      // overlay: 12..74.5 MB

    embed_kernel<<<MM, 256, 0, stream>>>(ids, emb, pos, h);

    for (int l = 0; l < 2; l++) {
        exc_kernel<<<1, 64, 0, stream>>>(propW + l * 16, propb + l * 4, sc);
        ln_bf16_kernel<<<MM, 256, 0, stream>>>(h, hn, ln1g + (long)l * D, ln1b + (long)l * D);
        cvtcat_kernel<<<1024, 256, 0, stream>>>(
            baseW + (long)l * D * D, W1 + (long)l * 4 * HH * D, Wcat);
        scale_w2_kernel<<<2048, 256, 0, stream>>>(
            W2 + (long)l * 4 * D * HH, gate + (long)l * 4 * D, tors, sc, W2eff);
        // {base -> C(f32), t = gelu(hn @ W1^T)} in ONE GEMM: N = 3072
        gemm_t<3><<<dim3(16, 24), 256, 0, stream>>>(
            hn, Wcat, C, t, 1024, 1024, 0);
        // C += t @ W2eff^T, split-K x4 (atomicAdd)
        gemm_t<4><<<dim3(16, 8, 4), 256, 0, stream>>>(
            t, W2eff, C, nullptr, 512, 2048, 1024);
        resln_kernel<<<MM, 256, 0, stream>>>(h, C, ln2g + (long)l * D, ln2b + (long)l * D);
    }

    ln_bf16_kernel<<<MM, 256, 0, stream>>>(h, hn, outg, outb);
    cvt_kernel<<<2048, 256, 0, stream>>>(lmW, lmWbf, VV * D / 4);
    // lm_head: 256^2 frag-prefetch schedule + NT output stores
    gemm256_kernel<<<dim3(8, 125), 512, 0, stream>>>(hn, lmWbf, (float*)d_out);
}